// Round 2
// baseline (689.585 us; speedup 1.0000x reference)
//
#include <hip/hip_runtime.h>

// Neural CDE forward, fused persistent kernel with SPLIT-F16 MFMA.
// Every MFMA operand x is represented as x_hi + x_lo (both f16), and each
// GEMM tile does 3 MFMAs: ah@Wh + ah@Wl + al@Wh -> f32 acc. Effective
// operand precision ~2^-22, near-f32, while keeping matrix-core throughput.
// z is authoritative in f32 LDS; per-step noise ~6e-6 abs vs f16's ~1e-2.

#define NBLK 256
#define NT   512
#define RB   16     // batch rows per block
#define T_LEN 166
#define IC   8
#define HID  64
#define MW   128    // MLP width
#define NF   512    // IC*HID

typedef _Float16 half8 __attribute__((ext_vector_type(8)));
typedef float    f32x4 __attribute__((ext_vector_type(4)));

__device__ __forceinline__ float fast_tanh(float x) {
    float e = __expf(2.0f * x);
    return 1.0f - 2.0f / (e + 1.0f);
}

__device__ __forceinline__ void split_f16(float v, _Float16& hi, _Float16& lo) {
    hi = (_Float16)v;
    lo = (_Float16)(v - (float)hi);
}

__global__ __launch_bounds__(NT, 2)
void cde_fused(const float* __restrict__ u0, const float* __restrict__ coeffs,
               const float* __restrict__ W1, const float* __restrict__ b1,
               const float* __restrict__ W2, const float* __restrict__ b2,
               const float* __restrict__ Wi, const float* __restrict__ bi,
               const float* __restrict__ Wr, const float* __restrict__ br,
               float* __restrict__ out)
{
    // LDS: swizzled split-f16 tiles for MFMA A-operands + fp32 state.
    __shared__ __align__(16) unsigned char hh[RB * 256];   // h hi: 16 x 128 f16
    __shared__ __align__(16) unsigned char hl[RB * 256];   // h lo
    __shared__ __align__(16) unsigned char zh[RB * 128];   // z hi: 16 x 64 f16
    __shared__ __align__(16) unsigned char zl[RB * 128];   // z lo
    __shared__ float zbuf[RB * HID];                       // z fp32 (authoritative)
    __shared__ float dxs[RB * IC];

    const int tid  = threadIdx.x;
    const int lane = tid & 63;
    const int w    = tid >> 6;      // wave 0..7
    const int l15  = lane & 15;
    const int lq   = lane >> 4;     // 0..3
    const int b0   = blockIdx.x * RB;

    // ---- stage split weights into registers ----
    // B-fragment: lane l holds B[k = kt*32 + (l>>4)*8 + j][col = nt*16 + (l&15)].
    // (Any consistent k-permutation between A and B fragments cancels.)
    half8 w1h[2], w1l[2];
    #pragma unroll
    for (int kt = 0; kt < 2; ++kt) {
        const int krow = kt * 32 + lq * 8;
        const int ncol = w * 16 + l15;          // GEMM1 ntile = wave id
        half8 vh, vl;
        #pragma unroll
        for (int j = 0; j < 8; ++j) {
            _Float16 hi, lo;
            split_f16(W1[(krow + j) * MW + ncol], hi, lo);
            vh[j] = hi; vl[j] = lo;
        }
        w1h[kt] = vh; w1l[kt] = vl;
    }
    half8 w2h[16], w2l[16];                     // wave's 4 ntiles x 4 ktiles
    #pragma unroll
    for (int q = 0; q < 4; ++q) {
        #pragma unroll
        for (int kt = 0; kt < 4; ++kt) {
            const int nt   = w * 4 + q;
            const int krow = kt * 32 + lq * 8;
            const int ncol = nt * 16 + l15;
            half8 vh, vl;
            #pragma unroll
            for (int j = 0; j < 8; ++j) {
                _Float16 hi, lo;
                split_f16(W2[(krow + j) * NF + ncol], hi, lo);
                vh[j] = hi; vl[j] = lo;
            }
            w2h[q * 4 + kt] = vh; w2l[q * 4 + kt] = vl;
        }
    }
    const float b1r = b1[w * 16 + l15];
    float b2r[4];
    #pragma unroll
    for (int q = 0; q < 4; ++q) b2r[q] = b2[(w * 4 + q) * 16 + l15];

    float wr0 = 0.f, wr1 = 0.f, wr2 = 0.f, wr3 = 0.f;
    const float brv = br[0];
    if (tid < 256) {
        const int seg = tid & 15;
        wr0 = Wr[seg * 4 + 0]; wr1 = Wr[seg * 4 + 1];
        wr2 = Wr[seg * 4 + 2]; wr3 = Wr[seg * 4 + 3];
    }

    // ---- z0 = u0 @ Wi + bi ----
    #pragma unroll
    for (int s = 0; s < 2; ++s) {
        const int o = tid + NT * s;              // 16 rows x 64 cols
        const int r = o >> 6, k = o & 63;
        float acc = bi[k];
        #pragma unroll
        for (int c = 0; c < 7; ++c) acc += u0[(b0 + r) * 7 + c] * Wi[c * HID + k];
        zbuf[r * HID + k] = acc;
        const int byte = r * 128 + ((k * 2) ^ ((r & 7) << 4));   // XOR-swizzle
        _Float16 hi, lo; split_f16(acc, hi, lo);
        *(_Float16*)(zh + byte) = hi;
        *(_Float16*)(zl + byte) = lo;
    }
    __syncthreads();

    for (int t = 0; t < T_LEN; ++t) {
        // ---- readout: out[b,t] = z_t @ Wr + br ----
        if (tid < 256) {
            const int r = tid >> 4, seg = tid & 15;
            const float* zr = zbuf + r * HID + seg * 4;
            float p = zr[0] * wr0 + zr[1] * wr1 + zr[2] * wr2 + zr[3] * wr3;
            p += __shfl_xor(p, 1, 64);
            p += __shfl_xor(p, 2, 64);
            p += __shfl_xor(p, 4, 64);
            p += __shfl_xor(p, 8, 64);
            if (seg == 0) out[(size_t)(b0 + r) * T_LEN + t] = p + brv;
        }
        if (t == T_LEN - 1) break;

        // ---- dx_t ----
        if (tid < 128) {
            const int r = tid >> 3, i = tid & 7;
            const float* cp = coeffs + ((size_t)(b0 + r) * T_LEN + t) * IC + i;
            dxs[r * IC + i] = cp[IC] - cp[0];
        }

        // ---- GEMM1: h = relu(z @ W1 + b1), split-f16, wave w = ntile w ----
        f32x4 acc1 = {0.f, 0.f, 0.f, 0.f};
        #pragma unroll
        for (int kt = 0; kt < 2; ++kt) {
            const int off = (kt * 32 + lq * 8) * 2;
            const int swz = l15 * 128 + (off ^ ((l15 & 7) << 4));
            const half8 ah = *(const half8*)(zh + swz);
            const half8 al = *(const half8*)(zl + swz);
            acc1 = __builtin_amdgcn_mfma_f32_16x16x32_f16(ah, w1h[kt], acc1, 0, 0, 0);
            acc1 = __builtin_amdgcn_mfma_f32_16x16x32_f16(ah, w1l[kt], acc1, 0, 0, 0);
            acc1 = __builtin_amdgcn_mfma_f32_16x16x32_f16(al, w1h[kt], acc1, 0, 0, 0);
        }
        #pragma unroll
        for (int r = 0; r < 4; ++r) {
            const float hv   = fmaxf(acc1[r] + b1r, 0.0f);
            const int   hrow = lq * 4 + r;                    // D: row=(l>>4)*4+r
            const int   col  = w * 16 + l15;                  //    col=l&15
            const int   byte = hrow * 256 + ((col * 2) ^ ((hrow & 7) << 4));
            _Float16 hi, lo; split_f16(hv, hi, lo);
            *(_Float16*)(hh + byte) = hi;
            *(_Float16*)(hl + byte) = lo;
        }
        __syncthreads();

        // ---- GEMM2 + tanh + z update ----
        half8 a2h[4], a2l[4];
        #pragma unroll
        for (int kt = 0; kt < 4; ++kt) {
            const int off = (kt * 32 + lq * 8) * 2;
            const int swz = l15 * 256 + (off ^ ((l15 & 7) << 4));
            a2h[kt] = *(const half8*)(hh + swz);
            a2l[kt] = *(const half8*)(hl + swz);
        }
        const int i = lane & 7;
        #pragma unroll
        for (int q = 0; q < 4; ++q) {
            f32x4 acc = {0.f, 0.f, 0.f, 0.f};
            #pragma unroll
            for (int kt = 0; kt < 4; ++kt) {
                acc = __builtin_amdgcn_mfma_f32_16x16x32_f16(a2h[kt], w2h[q * 4 + kt], acc, 0, 0, 0);
                acc = __builtin_amdgcn_mfma_f32_16x16x32_f16(a2h[kt], w2l[q * 4 + kt], acc, 0, 0, 0);
                acc = __builtin_amdgcn_mfma_f32_16x16x32_f16(a2l[kt], w2h[q * 4 + kt], acc, 0, 0, 0);
            }
            const int nt = w * 4 + q;
            const int kh = nt * 2 + (l15 >> 3);   // hidden unit this lane-group owns
            #pragma unroll
            for (int r = 0; r < 4; ++r) {
                const int row = lq * 4 + r;
                const float f = fast_tanh(acc[r] + b2r[q]);
                float s = f * dxs[row * IC + i];
                s += __shfl_xor(s, 1, 64);
                s += __shfl_xor(s, 2, 64);
                s += __shfl_xor(s, 4, 64);
                if (i == 0) {                      // unique owner of (row, kh)
                    const float zn = zbuf[row * HID + kh] + s;
                    zbuf[row * HID + kh] = zn;
                    const int byte = row * 128 + ((kh * 2) ^ ((row & 7) << 4));
                    _Float16 hi, lo; split_f16(zn, hi, lo);
                    *(_Float16*)(zh + byte) = hi;
                    *(_Float16*)(zl + byte) = lo;
                }
            }
        }
        __syncthreads();
    }
}

extern "C" void kernel_launch(void* const* d_in, const int* in_sizes, int n_in,
                              void* d_out, int out_size, void* d_ws, size_t ws_size,
                              hipStream_t stream) {
    const float* u0     = (const float*)d_in[0];
    const float* coeffs = (const float*)d_in[1];
    const float* W1     = (const float*)d_in[2];
    const float* b1     = (const float*)d_in[3];
    const float* W2     = (const float*)d_in[4];
    const float* b2     = (const float*)d_in[5];
    const float* Wi     = (const float*)d_in[6];
    const float* bi     = (const float*)d_in[7];
    const float* Wr     = (const float*)d_in[8];
    const float* br     = (const float*)d_in[9];
    cde_fused<<<NBLK, NT, 0, stream>>>(u0, coeffs, W1, b1, W2, b2, Wi, bi, Wr, br,
                                       (float*)d_out);
}

// Round 3
// 320.152 us; speedup vs baseline: 2.1539x; 2.1539x over previous
//
#include <hip/hip_runtime.h>

// Neural CDE forward, fused persistent kernel, split-f16 MFMA, TRANSPOSED
// GEMMs: D = W^T @ x^T via mfma(Wfrag, xfrag) so the MFMA output puts
// batch = lane&15 and output-channels = registers. This makes the IC=8
// contraction 4 in-lane FMAs + ONE shfl_xor(16) (was 3 shuffles x 16),
// the h epilogue a single ds_write_b64 pair (was 8 scattered b16 stores),
// and the z update conflict-free (padded zbuf).
// Numerics: every operand x = x_hi + x_lo (f16 pair), 3 MFMAs per tile
// (Wh@xh + Wl@xh + Wh@xl) into f32 acc -> ~2^-22 effective precision.

#define NBLK 256
#define NT   512
#define RB   16     // batch rows per block
#define T_LEN 166
#define IC   8
#define HID  64
#define MW   128    // MLP width
#define NF   512    // IC*HID
#define ZSTR 65     // padded zbuf row stride (f32) -> conflict-free RMW
#define DXSTR 12    // padded dx row stride (f32), keeps b128 2-way max

typedef _Float16 half8 __attribute__((ext_vector_type(8)));
typedef _Float16 half4 __attribute__((ext_vector_type(4)));
typedef float    f32x4 __attribute__((ext_vector_type(4)));

__device__ __forceinline__ float fast_tanh(float x) {
    // tanh(x) = 1 - 2/(exp(2x)+1); v_rcp_f32 (~1 ulp) instead of exact div.
    float e = __expf(2.0f * x);
    return 1.0f - 2.0f * __builtin_amdgcn_rcpf(e + 1.0f);
}

__global__ __launch_bounds__(NT, 2)
void cde_fused(const float* __restrict__ u0, const float* __restrict__ coeffs,
               const float* __restrict__ W1, const float* __restrict__ b1,
               const float* __restrict__ W2, const float* __restrict__ b2,
               const float* __restrict__ Wi, const float* __restrict__ bi,
               const float* __restrict__ Wr, const float* __restrict__ br,
               float* __restrict__ out)
{
    __shared__ __align__(16) unsigned char hh[RB * 256];   // h hi: 16 x 128 f16 (swizzled)
    __shared__ __align__(16) unsigned char hl[RB * 256];   // h lo
    __shared__ __align__(16) unsigned char zh[RB * 128];   // z hi: 16 x 64 f16 (swizzled)
    __shared__ __align__(16) unsigned char zl[RB * 128];   // z lo
    __shared__ float zbuf[RB * ZSTR];                      // z fp32 authority (padded)
    __shared__ __align__(16) float dxp[RB * DXSTR];        // dx per row (padded)

    const int tid  = threadIdx.x;
    const int lane = tid & 63;
    const int w    = tid >> 6;      // wave 0..7
    const int l15  = lane & 15;     // batch row this lane owns in MFMA D
    const int lq   = lane >> 4;     // 0..3
    const int swzr = (l15 & 7) << 4;
    const int b0   = blockIdx.x * RB;

    // ---- stage split weights into registers (A-fragments of W^T) ----
    // Fragment map (verified by the round-2 passing kernel): lane l supplies
    // element [idx0 = l&15][k = (l>>4)*8 + j] of its operand.
    half8 w1h[2], w1l[2];
    #pragma unroll
    for (int kt = 0; kt < 2; ++kt) {
        const int krow = kt * 32 + lq * 8;
        const int ncol = w * 16 + l15;          // GEMM1 output channel tile = wave
        half8 vh, vl;
        #pragma unroll
        for (int j = 0; j < 8; ++j) {
            const float x = W1[(krow + j) * MW + ncol];
            const _Float16 hi = (_Float16)x;
            vh[j] = hi; vl[j] = (_Float16)(x - (float)hi);
        }
        w1h[kt] = vh; w1l[kt] = vl;
    }
    half8 w2h[16], w2l[16];                     // wave's 4 ntiles x 4 ktiles
    #pragma unroll
    for (int q = 0; q < 4; ++q) {
        #pragma unroll
        for (int kt = 0; kt < 4; ++kt) {
            const int krow = kt * 32 + lq * 8;
            const int ncol = (w * 4 + q) * 16 + l15;
            half8 vh, vl;
            #pragma unroll
            for (int j = 0; j < 8; ++j) {
                const float x = W2[(krow + j) * NF + ncol];
                const _Float16 hi = (_Float16)x;
                vh[j] = hi; vl[j] = (_Float16)(x - (float)hi);
            }
            w2h[q * 4 + kt] = vh; w2l[q * 4 + kt] = vl;
        }
    }
    const f32x4 b1v = *(const f32x4*)(b1 + w * 16 + lq * 4);
    f32x4 b2v[4];
    #pragma unroll
    for (int q = 0; q < 4; ++q)
        b2v[q] = *(const f32x4*)(b2 + (w * 4 + q) * 16 + lq * 4);

    float wr0 = 0.f, wr1 = 0.f, wr2 = 0.f, wr3 = 0.f;
    const float brv = br[0];
    if (tid < 256) {
        const int seg = tid & 15;
        wr0 = Wr[seg * 4 + 0]; wr1 = Wr[seg * 4 + 1];
        wr2 = Wr[seg * 4 + 2]; wr3 = Wr[seg * 4 + 3];
    }

    // ---- z0 = u0 @ Wi + bi ----
    #pragma unroll
    for (int s = 0; s < 2; ++s) {
        const int o = tid + NT * s;              // 16 rows x 64 cols
        const int r = o >> 6, k = o & 63;
        float acc = bi[k];
        #pragma unroll
        for (int c = 0; c < 7; ++c) acc += u0[(b0 + r) * 7 + c] * Wi[c * HID + k];
        zbuf[r * ZSTR + k] = acc;
        const int byte = r * 128 + ((k * 2) ^ ((r & 7) << 4));
        const _Float16 hi = (_Float16)acc;
        *(_Float16*)(zh + byte) = hi;
        *(_Float16*)(zl + byte) = (_Float16)(acc - (float)hi);
    }
    __syncthreads();

    for (int t = 0; t < T_LEN; ++t) {
        // ---- readout: out[b,t] = z_t @ Wr + br ----
        if (tid < 256) {
            const int r = tid >> 4, seg = tid & 15;
            const float* zr = zbuf + r * ZSTR + seg * 4;
            float p = zr[0] * wr0 + zr[1] * wr1 + zr[2] * wr2 + zr[3] * wr3;
            p += __shfl_xor(p, 1, 64);
            p += __shfl_xor(p, 2, 64);
            p += __shfl_xor(p, 4, 64);
            p += __shfl_xor(p, 8, 64);
            if (seg == 0) out[(size_t)(b0 + r) * T_LEN + t] = p + brv;
        }
        if (t == T_LEN - 1) break;

        // ---- dx_t (per-row layout for the b128 read below) ----
        if (tid < 128) {
            const int r = tid >> 3, i = tid & 7;
            const float* cp = coeffs + ((size_t)(b0 + r) * T_LEN + t) * IC + i;
            dxp[r * DXSTR + i] = cp[IC] - cp[0];
        }

        // ---- GEMM1 (transposed): h^T = W1^T @ z^T, relu, store split ----
        f32x4 acc1 = {0.f, 0.f, 0.f, 0.f};
        #pragma unroll
        for (int kt = 0; kt < 2; ++kt) {
            const int off = l15 * 128 + ((kt * 64 + lq * 16) ^ swzr);
            const half8 zfh = *(const half8*)(zh + off);
            const half8 zfl = *(const half8*)(zl + off);
            acc1 = __builtin_amdgcn_mfma_f32_16x16x32_f16(w1h[kt], zfh, acc1, 0, 0, 0);
            acc1 = __builtin_amdgcn_mfma_f32_16x16x32_f16(w1l[kt], zfh, acc1, 0, 0, 0);
            acc1 = __builtin_amdgcn_mfma_f32_16x16x32_f16(w1h[kt], zfl, acc1, 0, 0, 0);
        }
        // lane owns channels c = w*16 + lq*4 + r of batch row l15 (consecutive!)
        half4 ph, pl;
        #pragma unroll
        for (int r = 0; r < 4; ++r) {
            const float hv = fmaxf(acc1[r] + b1v[r], 0.0f);
            const _Float16 hi = (_Float16)hv;
            ph[r] = hi; pl[r] = (_Float16)(hv - (float)hi);
        }
        const int hoff = l15 * 256 + ((w * 32 + lq * 8) ^ swzr);
        *(half4*)(hh + hoff) = ph;
        *(half4*)(hl + hoff) = pl;
        __syncthreads();

        // ---- GEMM2 (transposed) + tanh + i-contraction + z update ----
        half8 bhf[4], blf[4];
        #pragma unroll
        for (int kt = 0; kt < 4; ++kt) {
            const int off = l15 * 256 + ((kt * 64 + lq * 16) ^ swzr);
            bhf[kt] = *(const half8*)(hh + off);
            blf[kt] = *(const half8*)(hl + off);
        }
        const f32x4 dxv = *(const f32x4*)(dxp + l15 * DXSTR + (lq & 1) * 4);
        #pragma unroll
        for (int q = 0; q < 4; ++q) {
            f32x4 acc = {0.f, 0.f, 0.f, 0.f};
            #pragma unroll
            for (int kt = 0; kt < 4; ++kt) {
                acc = __builtin_amdgcn_mfma_f32_16x16x32_f16(w2h[q * 4 + kt], bhf[kt], acc, 0, 0, 0);
                acc = __builtin_amdgcn_mfma_f32_16x16x32_f16(w2l[q * 4 + kt], bhf[kt], acc, 0, 0, 0);
                acc = __builtin_amdgcn_mfma_f32_16x16x32_f16(w2h[q * 4 + kt], blf[kt], acc, 0, 0, 0);
            }
            // lane owns f-cols n = (w*4+q)*16 + lq*4 + r for batch l15;
            // i = n&7 = (lq&1)*4 + r; h-unit kh = (w*4+q)*2 + (lq>>1).
            float s = 0.f;
            #pragma unroll
            for (int r = 0; r < 4; ++r) {
                const float f = fast_tanh(acc[r] + b2v[q][r]);
                s = fmaf(f, dxv[r], s);
            }
            s += __shfl_xor(s, 16, 64);          // combine i0-3 with i4-7
            if ((lq & 1) == 0) {
                const int kh = (w * 4 + q) * 2 + (lq >> 1);
                const float zn = zbuf[l15 * ZSTR + kh] + s;
                zbuf[l15 * ZSTR + kh] = zn;
                const _Float16 hi = (_Float16)zn;
                const int zoff = l15 * 128 + ((kh * 2) ^ swzr);
                *(_Float16*)(zh + zoff) = hi;
                *(_Float16*)(zl + zoff) = (_Float16)(zn - (float)hi);
            }
        }
        __syncthreads();
    }
}

extern "C" void kernel_launch(void* const* d_in, const int* in_sizes, int n_in,
                              void* d_out, int out_size, void* d_ws, size_t ws_size,
                              hipStream_t stream) {
    const float* u0     = (const float*)d_in[0];
    const float* coeffs = (const float*)d_in[1];
    const float* W1     = (const float*)d_in[2];
    const float* b1     = (const float*)d_in[3];
    const float* W2     = (const float*)d_in[4];
    const float* b2     = (const float*)d_in[5];
    const float* Wi     = (const float*)d_in[6];
    const float* bi     = (const float*)d_in[7];
    const float* Wr     = (const float*)d_in[8];
    const float* br     = (const float*)d_in[9];
    cde_fused<<<NBLK, NT, 0, stream>>>(u0, coeffs, W1, b1, W2, b2, Wi, bi, Wr, br,
                                       (float*)d_out);
}

// Round 4
// 305.556 us; speedup vs baseline: 2.2568x; 1.0478x over previous
//
#include <hip/hip_runtime.h>

// Neural CDE forward, fused persistent kernel, split-f16 MFMA, transposed
// GEMMs (batch = lane&15 in MFMA D). Round-4 changes vs round 3:
//  - z is REGISTER-RESIDENT: after shfl_xor(16)+shfl_xor(32), lane lq==0 of
//    wave w owns all 8 consecutive channels [8w,8w+8) of batch l15. z-update
//    is 8 in-register adds; zh/zl writeback is 2 masked b128 stores
//    (was 4+4 b32 RMW + 8 b16 stores). zbuf deleted.
//  - readout via register partials: owner dots z8 with Wr (wave-uniform),
//    writes one b32 partial; wave 7 finalizes out[:,t] (read2 + 2 shfl).
//  - dx: per-lane register stream of 16B coeff chunks, one global dwordx4
//    per wave per step, prefetched at loop top; dxp LDS deleted.
//  - raw barriers (lgkmcnt(0) only) so the coeff prefetch survives.
// Numerics unchanged: split-f16 (hi+lo), 3 MFMAs per tile, f32 state.

#define NBLK 256
#define NT   512
#define RB   16
#define T_LEN 166
#define NSTEP 165
#define IC   8
#define HID  64
#define MW   128
#define NF   512

typedef _Float16 half8 __attribute__((ext_vector_type(8)));
typedef _Float16 half4 __attribute__((ext_vector_type(4)));
typedef float    f32x4 __attribute__((ext_vector_type(4)));

__device__ __forceinline__ float fast_tanh(float x) {
    float e = __expf(2.0f * x);
    return 1.0f - 2.0f * __builtin_amdgcn_rcpf(e + 1.0f);
}

__device__ __forceinline__ void bar_lgkm() {
    asm volatile("s_waitcnt lgkmcnt(0)" ::: "memory");
    __builtin_amdgcn_s_barrier();
    __builtin_amdgcn_sched_barrier(0);
}

__global__ __launch_bounds__(NT, 2)
void cde_fused(const float* __restrict__ u0, const float* __restrict__ coeffs,
               const float* __restrict__ W1, const float* __restrict__ b1,
               const float* __restrict__ W2, const float* __restrict__ b2,
               const float* __restrict__ Wi, const float* __restrict__ bi,
               const float* __restrict__ Wr, const float* __restrict__ br,
               float* __restrict__ out)
{
    __shared__ __align__(16) unsigned char hh[RB * 256];   // h hi: 16 x 128 f16 (swizzled)
    __shared__ __align__(16) unsigned char hl[RB * 256];   // h lo
    __shared__ __align__(16) unsigned char zh[RB * 128];   // z hi: 16 x 64 f16 (swizzled)
    __shared__ __align__(16) unsigned char zl[RB * 128];   // z lo
    __shared__ float part[8][17];                          // readout partials [wave][batch]

    const int tid  = threadIdx.x;
    const int lane = tid & 63;
    const int w    = tid >> 6;      // wave 0..7
    const int l15  = lane & 15;     // batch row in MFMA D
    const int lq   = lane >> 4;     // 0..3
    const int swzr = (l15 & 7) << 4;
    const int b0   = blockIdx.x * RB;

    // ---- stage split weights into registers (A-fragments of W^T) ----
    half8 w1h[2], w1l[2];
    #pragma unroll
    for (int kt = 0; kt < 2; ++kt) {
        const int krow = kt * 32 + lq * 8;
        const int ncol = w * 16 + l15;
        half8 vh, vl;
        #pragma unroll
        for (int j = 0; j < 8; ++j) {
            const float x = W1[(krow + j) * MW + ncol];
            const _Float16 hi = (_Float16)x;
            vh[j] = hi; vl[j] = (_Float16)(x - (float)hi);
        }
        w1h[kt] = vh; w1l[kt] = vl;
    }
    half8 w2h[16], w2l[16];
    #pragma unroll
    for (int q = 0; q < 4; ++q) {
        #pragma unroll
        for (int kt = 0; kt < 4; ++kt) {
            const int krow = kt * 32 + lq * 8;
            const int ncol = (w * 4 + q) * 16 + l15;
            half8 vh, vl;
            #pragma unroll
            for (int j = 0; j < 8; ++j) {
                const float x = W2[(krow + j) * NF + ncol];
                const _Float16 hi = (_Float16)x;
                vh[j] = hi; vl[j] = (_Float16)(x - (float)hi);
            }
            w2h[q * 4 + kt] = vh; w2l[q * 4 + kt] = vl;
        }
    }
    const f32x4 b1v = *(const f32x4*)(b1 + w * 16 + lq * 4);
    f32x4 b2v[4];
    #pragma unroll
    for (int q = 0; q < 4; ++q)
        b2v[q] = *(const f32x4*)(b2 + (w * 4 + q) * 16 + lq * 4);

    // Wr slice for this wave's 8 channels (wave-uniform address -> scalar)
    float wrs[8];
    #pragma unroll
    for (int j = 0; j < 8; ++j) wrs[j] = Wr[w * 8 + j];
    const float brv = br[0];

    // ---- z0: owner lane (lq==0) holds channels [8w, 8w+8) of batch l15 ----
    float z8[8];
    {
        float uu[7];
        const float* ur = u0 + (size_t)(b0 + l15) * 7;
        #pragma unroll
        for (int c = 0; c < 7; ++c) uu[c] = ur[c];
        #pragma unroll
        for (int j = 0; j < 8; ++j) {
            float a = bi[w * 8 + j];
            #pragma unroll
            for (int c = 0; c < 7; ++c) a = fmaf(uu[c], Wi[c * HID + w * 8 + j], a);
            z8[j] = a;
        }
    }
    {
        half8 hi8, lo8;
        #pragma unroll
        for (int j = 0; j < 8; ++j) {
            const _Float16 hi = (_Float16)z8[j];
            hi8[j] = hi; lo8[j] = (_Float16)(z8[j] - (float)hi);
        }
        if (lq == 0) {
            const int zoff = l15 * 128 + ((w * 16) ^ swzr);
            *(half8*)(zh + zoff) = hi8;
            *(half8*)(zl + zoff) = lo8;
            float rp = 0.f;
            #pragma unroll
            for (int j = 0; j < 8; ++j) rp = fmaf(z8[j], wrs[j], rp);
            part[w][l15] = rp;
        }
    }
    // per-lane coeff stream: 16B chunk (i = (lq&1)*4 .. +3) of row l15
    const float* cbase = coeffs + (size_t)(b0 + l15) * T_LEN * IC + (lq & 1) * 4;
    f32x4 ccur = *(const f32x4*)(cbase);
    __syncthreads();

    for (int t = 0; t < NSTEP; ++t) {
        // prefetch next coeff chunk (used after barrier 1)
        const f32x4 cnext = *(const f32x4*)(cbase + (size_t)(t + 1) * IC);

        // ---- finalize out[:, t] from partials of state t (wave 7 only) ----
        if (w == 7) {
            float v = part[lq][l15] + part[lq + 4][l15];
            v += __shfl_xor(v, 16, 64);
            v += __shfl_xor(v, 32, 64);
            if (lq == 0) out[(size_t)(b0 + l15) * T_LEN + t] = v + brv;
        }

        // ---- GEMM1: h^T = W1^T @ z^T, relu, split store ----
        f32x4 acc1 = {0.f, 0.f, 0.f, 0.f};
        #pragma unroll
        for (int kt = 0; kt < 2; ++kt) {
            const int off = l15 * 128 + ((kt * 64 + lq * 16) ^ swzr);
            const half8 zfh = *(const half8*)(zh + off);
            const half8 zfl = *(const half8*)(zl + off);
            acc1 = __builtin_amdgcn_mfma_f32_16x16x32_f16(w1h[kt], zfh, acc1, 0, 0, 0);
            acc1 = __builtin_amdgcn_mfma_f32_16x16x32_f16(w1l[kt], zfh, acc1, 0, 0, 0);
            acc1 = __builtin_amdgcn_mfma_f32_16x16x32_f16(w1h[kt], zfl, acc1, 0, 0, 0);
        }
        half4 ph, pl;
        #pragma unroll
        for (int r = 0; r < 4; ++r) {
            const float hv = fmaxf(acc1[r] + b1v[r], 0.0f);
            const _Float16 hi = (_Float16)hv;
            ph[r] = hi; pl[r] = (_Float16)(hv - (float)hi);
        }
        const int hoff = l15 * 256 + ((w * 32 + lq * 8) ^ swzr);
        *(half4*)(hh + hoff) = ph;
        *(half4*)(hl + hoff) = pl;
        bar_lgkm();

        // ---- GEMM2 + tanh + i-contraction + register z update ----
        half8 bhf[4], blf[4];
        #pragma unroll
        for (int kt = 0; kt < 4; ++kt) {
            const int off = l15 * 256 + ((kt * 64 + lq * 16) ^ swzr);
            bhf[kt] = *(const half8*)(hh + off);
            blf[kt] = *(const half8*)(hl + off);
        }
        const f32x4 dxv = cnext - ccur;
        #pragma unroll
        for (int q = 0; q < 4; ++q) {
            f32x4 acc = {0.f, 0.f, 0.f, 0.f};
            #pragma unroll
            for (int kt = 0; kt < 4; ++kt) {
                acc = __builtin_amdgcn_mfma_f32_16x16x32_f16(w2h[q * 4 + kt], bhf[kt], acc, 0, 0, 0);
                acc = __builtin_amdgcn_mfma_f32_16x16x32_f16(w2l[q * 4 + kt], bhf[kt], acc, 0, 0, 0);
                acc = __builtin_amdgcn_mfma_f32_16x16x32_f16(w2h[q * 4 + kt], blf[kt], acc, 0, 0, 0);
            }
            // lane (l15, lq): f-cols n=(w*4+q)*16+lq*4+r; i=(lq&1)*4+r; kh=8w+2q+(lq>>1)
            float s = 0.f;
            #pragma unroll
            for (int r = 0; r < 4; ++r)
                s = fmaf(fast_tanh(acc[r] + b2v[q][r]), dxv[r], s);
            const float tt = s + __shfl_xor(s, 16, 64);    // full sum, kh even (at lq<2)
            const float uu = __shfl_xor(tt, 32, 64);       // partner's: kh odd (at lq==0)
            z8[2 * q]     += tt;
            z8[2 * q + 1] += uu;
        }
        // owner writeback: 2 masked b128 stores + readout partial
        {
            half8 hi8, lo8;
            #pragma unroll
            for (int j = 0; j < 8; ++j) {
                const _Float16 hi = (_Float16)z8[j];
                hi8[j] = hi; lo8[j] = (_Float16)(z8[j] - (float)hi);
            }
            if (lq == 0) {
                const int zoff = l15 * 128 + ((w * 16) ^ swzr);
                *(half8*)(zh + zoff) = hi8;
                *(half8*)(zl + zoff) = lo8;
                float rp = 0.f;
                #pragma unroll
                for (int j = 0; j < 8; ++j) rp = fmaf(z8[j], wrs[j], rp);
                part[w][l15] = rp;
            }
        }
        ccur = cnext;
        bar_lgkm();
    }

    // ---- final readout: state 165 ----
    if (w == 7) {
        float v = part[lq][l15] + part[lq + 4][l15];
        v += __shfl_xor(v, 16, 64);
        v += __shfl_xor(v, 32, 64);
        if (lq == 0) out[(size_t)(b0 + l15) * T_LEN + NSTEP] = v + brv;
    }
}

extern "C" void kernel_launch(void* const* d_in, const int* in_sizes, int n_in,
                              void* d_out, int out_size, void* d_ws, size_t ws_size,
                              hipStream_t stream) {
    const float* u0     = (const float*)d_in[0];
    const float* coeffs = (const float*)d_in[1];
    const float* W1     = (const float*)d_in[2];
    const float* b1     = (const float*)d_in[3];
    const float* W2     = (const float*)d_in[4];
    const float* b2     = (const float*)d_in[5];
    const float* Wi     = (const float*)d_in[6];
    const float* bi     = (const float*)d_in[7];
    const float* Wr     = (const float*)d_in[8];
    const float* br     = (const float*)d_in[9];
    cde_fused<<<NBLK, NT, 0, stream>>>(u0, coeffs, W1, b1, W2, b2, Wi, bi, Wr, br,
                                       (float*)d_out);
}